// Round 20
// baseline (31.454 us; speedup 1.0000x reference)
//
#include <hip/hip_runtime.h>
#include <hip/hip_fp16.h>
#include <math.h>

#define D 64
#define NC 8
#define FK 8
#define NMIN 1440
#define TWO_PI_F 6.28318530717958647692f

#define TSZ ((size_t)NMIN * NC * D)   // table elements

// ---------------------------------------------------------------------------
// Kernel 1: build per-minute Fourier table T[m][n][d], stored as fp16.
// ---------------------------------------------------------------------------
__global__ __launch_bounds__(256) void build_table_kernel(
    const float* __restrict__ a0,
    const float* __restrict__ fa,
    const float* __restrict__ fb,
    __half* __restrict__ T)
{
    const int m = blockIdx.x;
    const int t = threadIdx.x;
    const int d  = t & (D - 1);
    const int n0 = t >> 6;
    const float angle = (float)m * (TWO_PI_F / (float)(NMIN - 1));

    float c[FK], s[FK];
    float s1, c1;
    sincosf(angle, &s1, &c1);
    c[0] = c1; s[0] = s1;
    {
        const float tw = 2.0f * c1;
        float cp = 1.0f, sp = 0.0f;
        float cc = c1, ss = s1;
#pragma unroll
        for (int k = 1; k < FK; ++k) {
            const float cn = fmaf(tw, cc, -cp);
            const float sn = fmaf(tw, ss, -sp);
            cp = cc; sp = ss; cc = cn; ss = sn;
            c[k] = cc; s[k] = ss;
        }
    }

#pragma unroll
    for (int j = 0; j < 2; ++j) {
        const int n = n0 + 4 * j;
        float v = a0[n * D + d];
#pragma unroll
        for (int k = 0; k < FK; ++k) {
            v = fmaf(c[k], fa[(n * FK + k) * D + d], v);
            v = fmaf(s[k], fb[(n * FK + k) * D + d], v);
        }
        T[(size_t)(m * NC + n) * D + d] = __float2half(v);
    }
}

// ---------------------------------------------------------------------------
// 8-lane all-reduce sum on the VALU via DPP (groups are 8-lane aligned).
// ---------------------------------------------------------------------------
__device__ __forceinline__ float grp8_allreduce_sum(float v) {
    int t;
    t = __builtin_amdgcn_update_dpp(0, __float_as_int(v), 0xB1, 0xF, 0xF, true);
    v += __int_as_float(t);
    t = __builtin_amdgcn_update_dpp(0, __float_as_int(v), 0x4E, 0xF, 0xF, true);
    v += __int_as_float(t);
    t = __builtin_amdgcn_update_dpp(0, __float_as_int(v), 0x141, 0xF, 0xF, true);
    v += __int_as_float(t);
    return v;
}

// ---------------------------------------------------------------------------
// PASS 1: scores + softmax -> P.  Short chain: emb -> dot -> reduce ->
// softmax -> store. Reads 33.5MB emb (coalesced), writes 4.2MB P.
// ---------------------------------------------------------------------------
__global__ __launch_bounds__(256) void score_kernel(
    const float* __restrict__ emb,
    const float* __restrict__ proto,
    float* __restrict__ out_P,
    int B)
{
    __shared__ float4 sproto[NC * (D / 4)];      // 2 KB
    if (threadIdx.x < NC * (D / 4)) {
        sproto[threadIdx.x] = ((const float4*)proto)[threadIdx.x];
    }
    __syncthreads();

    const int t = blockIdx.x * 256 + threadIdx.x;
    const int b = t >> 3;            // item index
    const int j = t & 7;             // lane-in-group
    if (b >= B) return;

    const float4* __restrict__ e4 = (const float4*)emb + (size_t)b * (D / 4);
    const float4 ev0 = e4[j];
    const float4 ev1 = e4[j + 8];

    float sc[NC];
#pragma unroll
    for (int n = 0; n < NC; ++n) {
        const float4 pa = sproto[n * (D / 4) + j];
        const float4 pb = sproto[n * (D / 4) + j + 8];
        float v = ev0.x * pa.x;
        v = fmaf(ev0.y, pa.y, v);
        v = fmaf(ev0.z, pa.z, v);
        v = fmaf(ev0.w, pa.w, v);
        v = fmaf(ev1.x, pb.x, v);
        v = fmaf(ev1.y, pb.y, v);
        v = fmaf(ev1.z, pb.z, v);
        v = fmaf(ev1.w, pb.w, v);
        sc[n] = v;
    }

#pragma unroll
    for (int n = 0; n < NC; ++n) {
        sc[n] = grp8_allreduce_sum(sc[n]);
    }

    // softmax(scores / tau), tau = 0.2 -> *5
    float mx = -1e30f;
#pragma unroll
    for (int n = 0; n < NC; ++n) { sc[n] *= 5.0f; mx = fmaxf(mx, sc[n]); }
    float sum = 0.0f;
#pragma unroll
    for (int n = 0; n < NC; ++n) { sc[n] = __expf(sc[n] - mx); sum += sc[n]; }
    const float inv = 1.0f / sum;
#pragma unroll
    for (int n = 0; n < NC; ++n) sc[n] *= inv;

    if (j == 0) {
        ((float4*)out_P)[(size_t)b * 2 + 0] = make_float4(sc[0], sc[1], sc[2], sc[3]);
    } else if (j == 4) {
        ((float4*)out_P)[(size_t)b * 2 + 1] = make_float4(sc[4], sc[5], sc[6], sc[7]);
    }
}

// ---------------------------------------------------------------------------
// PASS 2: out_emb = P . T[m].  Short chain: (P broadcast, theta) -> m ->
// fp16 T gather -> 64 FMA -> store. Reads P 4.2MB + theta 0.5MB + T (L2),
// writes 33.5MB coalesced.
// ---------------------------------------------------------------------------
__global__ __launch_bounds__(256) void mix_pass_kernel(
    const float* __restrict__ thetas,
    const float* __restrict__ P,
    const __half* __restrict__ T,
    float* __restrict__ out_emb,
    int B)
{
    const int t = blockIdx.x * 256 + threadIdx.x;
    const int b = t >> 3;            // item index
    const int j = t & 7;             // lane-in-group
    if (b >= B) return;

    // theta -> minute bucket
    const float th = thetas[b];                  // broadcast within group
    int m = (int)((th / TWO_PI_F) * (float)NMIN);
    m = m < 0 ? 0 : (m > NMIN - 1 ? NMIN - 1 : m);

    // P[b]: all 8 lanes read the same two float4s (broadcast-friendly)
    const float4* __restrict__ p4 = (const float4*)P + (size_t)b * 2;
    const float4 p0 = p4[0];
    const float4 p1 = p4[1];
    const float sc[NC] = { p0.x, p0.y, p0.z, p0.w, p1.x, p1.y, p1.z, p1.w };

    // gather fp16 T[m] rows and mix (lane j owns d 4j..4j+3 and 32+4j..35+4j)
    const uint2* __restrict__ t2 = (const uint2*)(T + (size_t)m * NC * D);
    float4 acc0 = make_float4(0.f, 0.f, 0.f, 0.f);
    float4 acc1 = make_float4(0.f, 0.f, 0.f, 0.f);
#pragma unroll
    for (int n = 0; n < NC; ++n) {
        const uint2 ua = t2[n * 16 + j];
        const uint2 ub = t2[n * 16 + j + 8];
        const float pw = sc[n];
        const float2 a01 = __half22float2(*(const __half2*)&ua.x);
        const float2 a23 = __half22float2(*(const __half2*)&ua.y);
        const float2 b01 = __half22float2(*(const __half2*)&ub.x);
        const float2 b23 = __half22float2(*(const __half2*)&ub.y);
        acc0.x = fmaf(pw, a01.x, acc0.x);
        acc0.y = fmaf(pw, a01.y, acc0.y);
        acc0.z = fmaf(pw, a23.x, acc0.z);
        acc0.w = fmaf(pw, a23.y, acc0.w);
        acc1.x = fmaf(pw, b01.x, acc1.x);
        acc1.y = fmaf(pw, b01.y, acc1.y);
        acc1.z = fmaf(pw, b23.x, acc1.z);
        acc1.w = fmaf(pw, b23.y, acc1.w);
    }

    float4* __restrict__ o4 = (float4*)out_emb + (size_t)b * (D / 4);
    o4[j]     = acc0;
    o4[j + 8] = acc1;
}

// ---------------------------------------------------------------------------
// Fallback (only if ws_size too small): fully fused, coefficients in LDS.
// ---------------------------------------------------------------------------
__global__ __launch_bounds__(256) void fused_fallback(
    const float* __restrict__ emb,
    const float* __restrict__ thetas,
    const float* __restrict__ proto,
    const float* __restrict__ a0,
    const float* __restrict__ fa,
    const float* __restrict__ fb,
    float* __restrict__ out_emb,
    float* __restrict__ out_P,
    int B)
{
    __shared__ float sp[NC * D];
    __shared__ float sa0[NC * D];
    __shared__ float sfa[NC * FK * D];
    __shared__ float sfb[NC * FK * D];
    for (int i = threadIdx.x; i < NC * D; i += 256) { sp[i] = proto[i]; sa0[i] = a0[i]; }
    for (int i = threadIdx.x; i < NC * FK * D; i += 256) { sfa[i] = fa[i]; sfb[i] = fb[i]; }
    __syncthreads();

    const int b = blockIdx.x * 256 + threadIdx.x;
    if (b >= B) return;

    const float4* __restrict__ e4  = (const float4*)(emb + (size_t)b * D);
    const float4* sp4  = (const float4*)sp;
    const float4* sa04 = (const float4*)sa0;
    const float4* sfa4 = (const float4*)sfa;
    const float4* sfb4 = (const float4*)sfb;

    float sc[NC];
#pragma unroll
    for (int n = 0; n < NC; ++n) sc[n] = 0.0f;
#pragma unroll
    for (int i = 0; i < D / 4; ++i) {
        const float4 ev = e4[i];
#pragma unroll
        for (int n = 0; n < NC; ++n) {
            const float4 pv = sp4[n * (D / 4) + i];
            sc[n] = fmaf(ev.x, pv.x, sc[n]);
            sc[n] = fmaf(ev.y, pv.y, sc[n]);
            sc[n] = fmaf(ev.z, pv.z, sc[n]);
            sc[n] = fmaf(ev.w, pv.w, sc[n]);
        }
    }
    float mx = -1e30f;
#pragma unroll
    for (int n = 0; n < NC; ++n) { sc[n] *= 5.0f; mx = fmaxf(mx, sc[n]); }
    float sum = 0.0f;
#pragma unroll
    for (int n = 0; n < NC; ++n) { sc[n] = __expf(sc[n] - mx); sum += sc[n]; }
    const float inv = 1.0f / sum;
#pragma unroll
    for (int n = 0; n < NC; ++n) sc[n] *= inv;

    const float th = thetas[b];
    int m = (int)((th / TWO_PI_F) * (float)NMIN);
    m = m < 0 ? 0 : (m > NMIN - 1 ? NMIN - 1 : m);
    const float angle = (float)m * (TWO_PI_F / (float)(NMIN - 1));
    float c[FK], s[FK];
#pragma unroll
    for (int k = 0; k < FK; ++k) sincosf(angle * (float)(k + 1), &s[k], &c[k]);

    float4 acc[D / 4];
#pragma unroll
    for (int i = 0; i < D / 4; ++i) acc[i] = make_float4(0.f, 0.f, 0.f, 0.f);
#pragma unroll
    for (int n = 0; n < NC; ++n) {
        const float pw = sc[n];
#pragma unroll
        for (int i = 0; i < D / 4; ++i) {
            float4 v = sa04[n * (D / 4) + i];
#pragma unroll
            for (int k = 0; k < FK; ++k) {
                const float4 av = sfa4[(n * FK + k) * (D / 4) + i];
                const float4 bv = sfb4[(n * FK + k) * (D / 4) + i];
                v.x = fmaf(c[k], av.x, v.x); v.x = fmaf(s[k], bv.x, v.x);
                v.y = fmaf(c[k], av.y, v.y); v.y = fmaf(s[k], bv.y, v.y);
                v.z = fmaf(c[k], av.z, v.z); v.z = fmaf(s[k], bv.z, v.z);
                v.w = fmaf(c[k], av.w, v.w); v.w = fmaf(s[k], bv.w, v.w);
            }
            acc[i].x = fmaf(pw, v.x, acc[i].x);
            acc[i].y = fmaf(pw, v.y, acc[i].y);
            acc[i].z = fmaf(pw, v.z, acc[i].z);
            acc[i].w = fmaf(pw, v.w, acc[i].w);
        }
    }
    float4* o4 = (float4*)(out_emb + (size_t)b * D);
#pragma unroll
    for (int i = 0; i < D / 4; ++i) o4[i] = acc[i];
    float4* op = (float4*)(out_P + (size_t)b * NC);
    op[0] = make_float4(sc[0], sc[1], sc[2], sc[3]);
    op[1] = make_float4(sc[4], sc[5], sc[6], sc[7]);
}

extern "C" void kernel_launch(void* const* d_in, const int* in_sizes, int n_in,
                              void* d_out, int out_size, void* d_ws, size_t ws_size,
                              hipStream_t stream)
{
    const float* emb    = (const float*)d_in[0];
    const float* thetas = (const float*)d_in[1];
    const float* proto  = (const float*)d_in[2];
    const float* a0     = (const float*)d_in[3];
    const float* fa     = (const float*)d_in[4];
    const float* fb     = (const float*)d_in[5];

    const int B = in_sizes[0] / D;           // 131072
    float* out_emb = (float*)d_out;
    float* out_P   = (float*)d_out + (size_t)B * D;

    const size_t table_bytes = TSZ * sizeof(__half);   // ~1.5 MB

    if (ws_size >= table_bytes) {
        __half* T = (__half*)d_ws;
        build_table_kernel<<<NMIN, 256, 0, stream>>>(a0, fa, fb, T);

        const long long total_threads = (long long)B * 8;
        const int blocks = (int)((total_threads + 255) / 256);  // 4096
        score_kernel<<<blocks, 256, 0, stream>>>(emb, proto, out_P, B);
        mix_pass_kernel<<<blocks, 256, 0, stream>>>(thetas, out_P, T, out_emb, B);
    } else {
        const int blocks = (B + 255) / 256;
        fused_fallback<<<blocks, 256, 0, stream>>>(emb, thetas, proto, a0, fa, fb,
                                                   out_emb, out_P, B);
    }
}

// Round 21
// 26.930 us; speedup vs baseline: 1.1680x; 1.1680x over previous
//
#include <hip/hip_runtime.h>
#include <hip/hip_fp16.h>
#include <math.h>

#define D 64
#define NC 8
#define FK 8
#define NMIN 1440
#define TWO_PI_F 6.28318530717958647692f

#define TSZ ((size_t)NMIN * NC * D)   // table elements

// ---------------------------------------------------------------------------
// Kernel 1: build per-minute Fourier table T[m][n][d], stored as fp16.
// Compute in fp32 (Chebyshev recurrence), round once to half on store.
// ---------------------------------------------------------------------------
__global__ __launch_bounds__(256) void build_table_kernel(
    const float* __restrict__ a0,
    const float* __restrict__ fa,
    const float* __restrict__ fb,
    __half* __restrict__ T)
{
    const int m = blockIdx.x;
    const int t = threadIdx.x;
    const int d  = t & (D - 1);
    const int n0 = t >> 6;
    const float angle = (float)m * (TWO_PI_F / (float)(NMIN - 1));

    float c[FK], s[FK];
    float s1, c1;
    sincosf(angle, &s1, &c1);
    c[0] = c1; s[0] = s1;
    {
        const float tw = 2.0f * c1;
        float cp = 1.0f, sp = 0.0f;
        float cc = c1, ss = s1;
#pragma unroll
        for (int k = 1; k < FK; ++k) {
            const float cn = fmaf(tw, cc, -cp);
            const float sn = fmaf(tw, ss, -sp);
            cp = cc; sp = ss; cc = cn; ss = sn;
            c[k] = cc; s[k] = ss;
        }
    }

#pragma unroll
    for (int j = 0; j < 2; ++j) {
        const int n = n0 + 4 * j;
        float v = a0[n * D + d];
#pragma unroll
        for (int k = 0; k < FK; ++k) {
            v = fmaf(c[k], fa[(n * FK + k) * D + d], v);
            v = fmaf(s[k], fb[(n * FK + k) * D + d], v);
        }
        T[(size_t)(m * NC + n) * D + d] = __float2half(v);
    }
}

// ---------------------------------------------------------------------------
// 8-lane all-reduce sum on the VALU via DPP (groups are 8-lane aligned).
// ---------------------------------------------------------------------------
__device__ __forceinline__ float grp8_allreduce_sum(float v) {
    int t;
    t = __builtin_amdgcn_update_dpp(0, __float_as_int(v), 0xB1, 0xF, 0xF, true);
    v += __int_as_float(t);
    t = __builtin_amdgcn_update_dpp(0, __float_as_int(v), 0x4E, 0xF, 0xF, true);
    v += __int_as_float(t);
    t = __builtin_amdgcn_update_dpp(0, __float_as_int(v), 0x141, 0xF, 0xF, true);
    v += __int_as_float(t);
    return v;
}

// ---------------------------------------------------------------------------
// Kernel 2 (round-17 best, 27.0us): 8 lanes per item; proto in LDS; DPP
// reduce; fp16 T gather prefetched into regs before the score/softmax chain.
// ---------------------------------------------------------------------------
__global__ __launch_bounds__(256) void mix_kernel8(
    const float* __restrict__ emb,
    const float* __restrict__ thetas,
    const float* __restrict__ proto,
    const __half* __restrict__ T,
    float* __restrict__ out_emb,
    float* __restrict__ out_P,
    int B)
{
    __shared__ float4 sproto[NC * (D / 4)];      // 2 KB
    if (threadIdx.x < NC * (D / 4)) {
        sproto[threadIdx.x] = ((const float4*)proto)[threadIdx.x];
    }
    __syncthreads();

    const int t = blockIdx.x * 256 + threadIdx.x;
    const int b = t >> 3;            // item index
    const int j = t & 7;             // lane-in-group
    if (b >= B) return;

    // --- theta -> minute bucket (first: unlocks T addresses) ---
    const float th = thetas[b];                  // broadcast within group
    int m = (int)((th / TWO_PI_F) * (float)NMIN);
    m = m < 0 ? 0 : (m > NMIN - 1 ? NMIN - 1 : m);

    // --- issue emb loads ---
    const float4* __restrict__ e4 = (const float4*)emb + (size_t)b * (D / 4);
    const float4 ev0 = e4[j];
    const float4 ev1 = e4[j + 8];

    // --- PREFETCH: issue all 16 T loads now; consumed only after softmax ---
    const uint2* __restrict__ t2 = (const uint2*)(T + (size_t)m * NC * D);
    uint2 ua[NC], ub[NC];
#pragma unroll
    for (int n = 0; n < NC; ++n) {
        ua[n] = t2[n * 16 + j];
        ub[n] = t2[n * 16 + j + 8];
    }

    // --- partial scores vs 8 prototypes (from LDS; waits only on emb) ---
    float sc[NC];
#pragma unroll
    for (int n = 0; n < NC; ++n) {
        const float4 pa = sproto[n * (D / 4) + j];
        const float4 pb = sproto[n * (D / 4) + j + 8];
        float v = ev0.x * pa.x;
        v = fmaf(ev0.y, pa.y, v);
        v = fmaf(ev0.z, pa.z, v);
        v = fmaf(ev0.w, pa.w, v);
        v = fmaf(ev1.x, pb.x, v);
        v = fmaf(ev1.y, pb.y, v);
        v = fmaf(ev1.z, pb.z, v);
        v = fmaf(ev1.w, pb.w, v);
        sc[n] = v;
    }

    // --- reduce across the 8-lane group (VALU/DPP) ---
#pragma unroll
    for (int n = 0; n < NC; ++n) {
        sc[n] = grp8_allreduce_sum(sc[n]);
    }

    // --- softmax(scores / tau), tau = 0.2 -> *5 ---
    float mx = -1e30f;
#pragma unroll
    for (int n = 0; n < NC; ++n) { sc[n] *= 5.0f; mx = fmaxf(mx, sc[n]); }
    float sum = 0.0f;
#pragma unroll
    for (int n = 0; n < NC; ++n) { sc[n] = __expf(sc[n] - mx); sum += sc[n]; }
    const float inv = 1.0f / sum;
#pragma unroll
    for (int n = 0; n < NC; ++n) sc[n] *= inv;

    // --- unpack prefetched T and mix ---
    float4 acc0 = make_float4(0.f, 0.f, 0.f, 0.f);
    float4 acc1 = make_float4(0.f, 0.f, 0.f, 0.f);
#pragma unroll
    for (int n = 0; n < NC; ++n) {
        const float pw = sc[n];
        const float2 a01 = __half22float2(*(const __half2*)&ua[n].x);
        const float2 a23 = __half22float2(*(const __half2*)&ua[n].y);
        const float2 b01 = __half22float2(*(const __half2*)&ub[n].x);
        const float2 b23 = __half22float2(*(const __half2*)&ub[n].y);
        acc0.x = fmaf(pw, a01.x, acc0.x);
        acc0.y = fmaf(pw, a01.y, acc0.y);
        acc0.z = fmaf(pw, a23.x, acc0.z);
        acc0.w = fmaf(pw, a23.y, acc0.w);
        acc1.x = fmaf(pw, b01.x, acc1.x);
        acc1.y = fmaf(pw, b01.y, acc1.y);
        acc1.z = fmaf(pw, b23.x, acc1.z);
        acc1.w = fmaf(pw, b23.y, acc1.w);
    }

    float4* __restrict__ o4 = (float4*)out_emb + (size_t)b * (D / 4);
    o4[j]     = acc0;
    o4[j + 8] = acc1;

    // --- P output: lanes 0 and 4 each write one float4 ---
    if (j == 0) {
        ((float4*)out_P)[(size_t)b * 2 + 0] = make_float4(sc[0], sc[1], sc[2], sc[3]);
    } else if (j == 4) {
        ((float4*)out_P)[(size_t)b * 2 + 1] = make_float4(sc[4], sc[5], sc[6], sc[7]);
    }
}

// ---------------------------------------------------------------------------
// Fallback (only if ws_size too small): fully fused, coefficients in LDS.
// ---------------------------------------------------------------------------
__global__ __launch_bounds__(256) void fused_fallback(
    const float* __restrict__ emb,
    const float* __restrict__ thetas,
    const float* __restrict__ proto,
    const float* __restrict__ a0,
    const float* __restrict__ fa,
    const float* __restrict__ fb,
    float* __restrict__ out_emb,
    float* __restrict__ out_P,
    int B)
{
    __shared__ float sp[NC * D];
    __shared__ float sa0[NC * D];
    __shared__ float sfa[NC * FK * D];
    __shared__ float sfb[NC * FK * D];
    for (int i = threadIdx.x; i < NC * D; i += 256) { sp[i] = proto[i]; sa0[i] = a0[i]; }
    for (int i = threadIdx.x; i < NC * FK * D; i += 256) { sfa[i] = fa[i]; sfb[i] = fb[i]; }
    __syncthreads();

    const int b = blockIdx.x * 256 + threadIdx.x;
    if (b >= B) return;

    const float4* __restrict__ e4  = (const float4*)(emb + (size_t)b * D);
    const float4* sp4  = (const float4*)sp;
    const float4* sa04 = (const float4*)sa0;
    const float4* sfa4 = (const float4*)sfa;
    const float4* sfb4 = (const float4*)sfb;

    float sc[NC];
#pragma unroll
    for (int n = 0; n < NC; ++n) sc[n] = 0.0f;
#pragma unroll
    for (int i = 0; i < D / 4; ++i) {
        const float4 ev = e4[i];
#pragma unroll
        for (int n = 0; n < NC; ++n) {
            const float4 pv = sp4[n * (D / 4) + i];
            sc[n] = fmaf(ev.x, pv.x, sc[n]);
            sc[n] = fmaf(ev.y, pv.y, sc[n]);
            sc[n] = fmaf(ev.z, pv.z, sc[n]);
            sc[n] = fmaf(ev.w, pv.w, sc[n]);
        }
    }
    float mx = -1e30f;
#pragma unroll
    for (int n = 0; n < NC; ++n) { sc[n] *= 5.0f; mx = fmaxf(mx, sc[n]); }
    float sum = 0.0f;
#pragma unroll
    for (int n = 0; n < NC; ++n) { sc[n] = __expf(sc[n] - mx); sum += sc[n]; }
    const float inv = 1.0f / sum;
#pragma unroll
    for (int n = 0; n < NC; ++n) sc[n] *= inv;

    const float th = thetas[b];
    int m = (int)((th / TWO_PI_F) * (float)NMIN);
    m = m < 0 ? 0 : (m > NMIN - 1 ? NMIN - 1 : m);
    const float angle = (float)m * (TWO_PI_F / (float)(NMIN - 1));
    float c[FK], s[FK];
#pragma unroll
    for (int k = 0; k < FK; ++k) sincosf(angle * (float)(k + 1), &s[k], &c[k]);

    float4 acc[D / 4];
#pragma unroll
    for (int i = 0; i < D / 4; ++i) acc[i] = make_float4(0.f, 0.f, 0.f, 0.f);
#pragma unroll
    for (int n = 0; n < NC; ++n) {
        const float pw = sc[n];
#pragma unroll
        for (int i = 0; i < D / 4; ++i) {
            float4 v = sa04[n * (D / 4) + i];
#pragma unroll
            for (int k = 0; k < FK; ++k) {
                const float4 av = sfa4[(n * FK + k) * (D / 4) + i];
                const float4 bv = sfb4[(n * FK + k) * (D / 4) + i];
                v.x = fmaf(c[k], av.x, v.x); v.x = fmaf(s[k], bv.x, v.x);
                v.y = fmaf(c[k], av.y, v.y); v.y = fmaf(s[k], bv.y, v.y);
                v.z = fmaf(c[k], av.z, v.z); v.z = fmaf(s[k], bv.z, v.z);
                v.w = fmaf(c[k], av.w, v.w); v.w = fmaf(s[k], bv.w, v.w);
            }
            acc[i].x = fmaf(pw, v.x, acc[i].x);
            acc[i].y = fmaf(pw, v.y, acc[i].y);
            acc[i].z = fmaf(pw, v.z, acc[i].z);
            acc[i].w = fmaf(pw, v.w, acc[i].w);
        }
    }
    float4* o4 = (float4*)(out_emb + (size_t)b * D);
#pragma unroll
    for (int i = 0; i < D / 4; ++i) o4[i] = acc[i];
    float4* op = (float4*)(out_P + (size_t)b * NC);
    op[0] = make_float4(sc[0], sc[1], sc[2], sc[3]);
    op[1] = make_float4(sc[4], sc[5], sc[6], sc[7]);
}

extern "C" void kernel_launch(void* const* d_in, const int* in_sizes, int n_in,
                              void* d_out, int out_size, void* d_ws, size_t ws_size,
                              hipStream_t stream)
{
    const float* emb    = (const float*)d_in[0];
    const float* thetas = (const float*)d_in[1];
    const float* proto  = (const float*)d_in[2];
    const float* a0     = (const float*)d_in[3];
    const float* fa     = (const float*)d_in[4];
    const float* fb     = (const float*)d_in[5];

    const int B = in_sizes[0] / D;           // 131072
    float* out_emb = (float*)d_out;
    float* out_P   = (float*)d_out + (size_t)B * D;

    const size_t table_bytes = TSZ * sizeof(__half);   // ~1.5 MB

    if (ws_size >= table_bytes) {
        __half* T = (__half*)d_ws;
        build_table_kernel<<<NMIN, 256, 0, stream>>>(a0, fa, fb, T);
        // 8 lanes per item: B*8 threads total
        const long long total_threads = (long long)B * 8;
        const int blocks = (int)((total_threads + 255) / 256);
        mix_kernel8<<<blocks, 256, 0, stream>>>(emb, thetas, proto, T, out_emb, out_P, B);
    } else {
        const int blocks = (B + 255) / 256;
        fused_fallback<<<blocks, 256, 0, stream>>>(emb, thetas, proto, a0, fa, fb,
                                                   out_emb, out_P, B);
    }
}

// Round 22
// 26.406 us; speedup vs baseline: 1.1912x; 1.0198x over previous
//
#include <hip/hip_runtime.h>
#include <hip/hip_fp16.h>
#include <math.h>

#define D 64
#define NC 8
#define FK 8
#define NMIN 1440
#define TWO_PI_F 6.28318530717958647692f

#define TSZ ((size_t)NMIN * NC * D)   // table elements

// ---------------------------------------------------------------------------
// Kernel 1: build per-minute Fourier table T[m][n][d], stored as fp16.
// ---------------------------------------------------------------------------
__global__ __launch_bounds__(256) void build_table_kernel(
    const float* __restrict__ a0,
    const float* __restrict__ fa,
    const float* __restrict__ fb,
    __half* __restrict__ T)
{
    const int m = blockIdx.x;
    const int t = threadIdx.x;
    const int d  = t & (D - 1);
    const int n0 = t >> 6;
    const float angle = (float)m * (TWO_PI_F / (float)(NMIN - 1));

    float c[FK], s[FK];
    float s1, c1;
    sincosf(angle, &s1, &c1);
    c[0] = c1; s[0] = s1;
    {
        const float tw = 2.0f * c1;
        float cp = 1.0f, sp = 0.0f;
        float cc = c1, ss = s1;
#pragma unroll
        for (int k = 1; k < FK; ++k) {
            const float cn = fmaf(tw, cc, -cp);
            const float sn = fmaf(tw, ss, -sp);
            cp = cc; sp = ss; cc = cn; ss = sn;
            c[k] = cc; s[k] = ss;
        }
    }

#pragma unroll
    for (int j = 0; j < 2; ++j) {
        const int n = n0 + 4 * j;
        float v = a0[n * D + d];
#pragma unroll
        for (int k = 0; k < FK; ++k) {
            v = fmaf(c[k], fa[(n * FK + k) * D + d], v);
            v = fmaf(s[k], fb[(n * FK + k) * D + d], v);
        }
        T[(size_t)(m * NC + n) * D + d] = __float2half(v);
    }
}

// ---------------------------------------------------------------------------
// 16-lane all-reduce sum on the VALU via DPP (verified rounds 10-11):
//   xor1=quad_perm(1,0,3,2)=0xB1, xor2=quad_perm(2,3,0,1)=0x4E,
//   xor~4=row_half_mirror=0x141, xor8=row_ror:8=0x128.
// ---------------------------------------------------------------------------
__device__ __forceinline__ float grp16_allreduce_sum(float v) {
    int t;
    t = __builtin_amdgcn_update_dpp(0, __float_as_int(v), 0xB1, 0xF, 0xF, true);
    v += __int_as_float(t);
    t = __builtin_amdgcn_update_dpp(0, __float_as_int(v), 0x4E, 0xF, 0xF, true);
    v += __int_as_float(t);
    t = __builtin_amdgcn_update_dpp(0, __float_as_int(v), 0x141, 0xF, 0xF, true);
    v += __int_as_float(t);
    t = __builtin_amdgcn_update_dpp(0, __float_as_int(v), 0x128, 0xF, 0xF, true);
    v += __int_as_float(t);
    return v;
}

// ---------------------------------------------------------------------------
// Kernel 2: SINGLE CHANGE vs round-17 best — 16 lanes per item instead of 8
// (A/B of lane count under the fp16+prefetch regime: 2x thread count /
// 2x concurrent waves per SIMD, half the per-thread prefetch state).
// Lane i owns float4 d-slice i; T row = 16 lanes x uint2 (4 halves).
// ---------------------------------------------------------------------------
__global__ __launch_bounds__(256) void mix_kernel16(
    const float* __restrict__ emb,
    const float* __restrict__ thetas,
    const float* __restrict__ proto,
    const __half* __restrict__ T,
    float* __restrict__ out_emb,
    float* __restrict__ out_P,
    int B)
{
    __shared__ float4 sproto[NC * (D / 4)];      // 2 KB
    if (threadIdx.x < NC * (D / 4)) {
        sproto[threadIdx.x] = ((const float4*)proto)[threadIdx.x];
    }
    __syncthreads();

    const int t = blockIdx.x * 256 + threadIdx.x;
    const int b = t >> 4;            // item index
    const int i = t & 15;            // d-slice index (float4 granularity)
    if (b >= B) return;

    // --- theta -> minute bucket (first: unlocks T addresses) ---
    const float th = thetas[b];                  // broadcast within group
    int m = (int)((th / TWO_PI_F) * (float)NMIN);
    m = m < 0 ? 0 : (m > NMIN - 1 ? NMIN - 1 : m);

    // --- issue emb load ---
    const float4 ev = ((const float4*)emb)[(size_t)b * (D / 4) + i];

    // --- PREFETCH: issue all 8 T loads now; consumed only after softmax ---
    const uint2* __restrict__ t2 = (const uint2*)(T + (size_t)m * NC * D);
    uint2 u[NC];
#pragma unroll
    for (int n = 0; n < NC; ++n) {
        u[n] = t2[n * 16 + i];
    }

    // --- partial scores vs 8 prototypes (from LDS; waits only on emb) ---
    float sc[NC];
#pragma unroll
    for (int n = 0; n < NC; ++n) {
        const float4 pv = sproto[n * (D / 4) + i];
        float v = ev.x * pv.x;
        v = fmaf(ev.y, pv.y, v);
        v = fmaf(ev.z, pv.z, v);
        v = fmaf(ev.w, pv.w, v);
        sc[n] = v;
    }

    // --- reduce across the 16-lane group (VALU/DPP) ---
#pragma unroll
    for (int n = 0; n < NC; ++n) {
        sc[n] = grp16_allreduce_sum(sc[n]);
    }

    // --- softmax(scores / tau), tau = 0.2 -> *5 ---
    float mx = -1e30f;
#pragma unroll
    for (int n = 0; n < NC; ++n) { sc[n] *= 5.0f; mx = fmaxf(mx, sc[n]); }
    float sum = 0.0f;
#pragma unroll
    for (int n = 0; n < NC; ++n) { sc[n] = __expf(sc[n] - mx); sum += sc[n]; }
    const float inv = 1.0f / sum;
#pragma unroll
    for (int n = 0; n < NC; ++n) sc[n] *= inv;

    // --- unpack prefetched T and mix ---
    float4 acc = make_float4(0.f, 0.f, 0.f, 0.f);
#pragma unroll
    for (int n = 0; n < NC; ++n) {
        const float pw = sc[n];
        const float2 a01 = __half22float2(*(const __half2*)&u[n].x);
        const float2 a23 = __half22float2(*(const __half2*)&u[n].y);
        acc.x = fmaf(pw, a01.x, acc.x);
        acc.y = fmaf(pw, a01.y, acc.y);
        acc.z = fmaf(pw, a23.x, acc.z);
        acc.w = fmaf(pw, a23.y, acc.w);
    }

    ((float4*)out_emb)[(size_t)b * (D / 4) + i] = acc;

    // --- P output: lanes 0 and 8 each write one float4 ---
    if (i == 0) {
        ((float4*)out_P)[(size_t)b * 2 + 0] = make_float4(sc[0], sc[1], sc[2], sc[3]);
    } else if (i == 8) {
        ((float4*)out_P)[(size_t)b * 2 + 1] = make_float4(sc[4], sc[5], sc[6], sc[7]);
    }
}

// ---------------------------------------------------------------------------
// Fallback (only if ws_size too small): fully fused, coefficients in LDS.
// ---------------------------------------------------------------------------
__global__ __launch_bounds__(256) void fused_fallback(
    const float* __restrict__ emb,
    const float* __restrict__ thetas,
    const float* __restrict__ proto,
    const float* __restrict__ a0,
    const float* __restrict__ fa,
    const float* __restrict__ fb,
    float* __restrict__ out_emb,
    float* __restrict__ out_P,
    int B)
{
    __shared__ float sp[NC * D];
    __shared__ float sa0[NC * D];
    __shared__ float sfa[NC * FK * D];
    __shared__ float sfb[NC * FK * D];
    for (int i = threadIdx.x; i < NC * D; i += 256) { sp[i] = proto[i]; sa0[i] = a0[i]; }
    for (int i = threadIdx.x; i < NC * FK * D; i += 256) { sfa[i] = fa[i]; sfb[i] = fb[i]; }
    __syncthreads();

    const int b = blockIdx.x * 256 + threadIdx.x;
    if (b >= B) return;

    const float4* __restrict__ e4  = (const float4*)(emb + (size_t)b * D);
    const float4* sp4  = (const float4*)sp;
    const float4* sa04 = (const float4*)sa0;
    const float4* sfa4 = (const float4*)sfa;
    const float4* sfb4 = (const float4*)sfb;

    float sc[NC];
#pragma unroll
    for (int n = 0; n < NC; ++n) sc[n] = 0.0f;
#pragma unroll
    for (int i = 0; i < D / 4; ++i) {
        const float4 ev = e4[i];
#pragma unroll
        for (int n = 0; n < NC; ++n) {
            const float4 pv = sp4[n * (D / 4) + i];
            sc[n] = fmaf(ev.x, pv.x, sc[n]);
            sc[n] = fmaf(ev.y, pv.y, sc[n]);
            sc[n] = fmaf(ev.z, pv.z, sc[n]);
            sc[n] = fmaf(ev.w, pv.w, sc[n]);
        }
    }
    float mx = -1e30f;
#pragma unroll
    for (int n = 0; n < NC; ++n) { sc[n] *= 5.0f; mx = fmaxf(mx, sc[n]); }
    float sum = 0.0f;
#pragma unroll
    for (int n = 0; n < NC; ++n) { sc[n] = __expf(sc[n] - mx); sum += sc[n]; }
    const float inv = 1.0f / sum;
#pragma unroll
    for (int n = 0; n < NC; ++n) sc[n] *= inv;

    const float th = thetas[b];
    int m = (int)((th / TWO_PI_F) * (float)NMIN);
    m = m < 0 ? 0 : (m > NMIN - 1 ? NMIN - 1 : m);
    const float angle = (float)m * (TWO_PI_F / (float)(NMIN - 1));
    float c[FK], s[FK];
#pragma unroll
    for (int k = 0; k < FK; ++k) sincosf(angle * (float)(k + 1), &s[k], &c[k]);

    float4 acc[D / 4];
#pragma unroll
    for (int i = 0; i < D / 4; ++i) acc[i] = make_float4(0.f, 0.f, 0.f, 0.f);
#pragma unroll
    for (int n = 0; n < NC; ++n) {
        const float pw = sc[n];
#pragma unroll
        for (int i = 0; i < D / 4; ++i) {
            float4 v = sa04[n * (D / 4) + i];
#pragma unroll
            for (int k = 0; k < FK; ++k) {
                const float4 av = sfa4[(n * FK + k) * (D / 4) + i];
                const float4 bv = sfb4[(n * FK + k) * (D / 4) + i];
                v.x = fmaf(c[k], av.x, v.x); v.x = fmaf(s[k], bv.x, v.x);
                v.y = fmaf(c[k], av.y, v.y); v.y = fmaf(s[k], bv.y, v.y);
                v.z = fmaf(c[k], av.z, v.z); v.z = fmaf(s[k], bv.z, v.z);
                v.w = fmaf(c[k], av.w, v.w); v.w = fmaf(s[k], bv.w, v.w);
            }
            acc[i].x = fmaf(pw, v.x, acc[i].x);
            acc[i].y = fmaf(pw, v.y, acc[i].y);
            acc[i].z = fmaf(pw, v.z, acc[i].z);
            acc[i].w = fmaf(pw, v.w, acc[i].w);
        }
    }
    float4* o4 = (float4*)(out_emb + (size_t)b * D);
#pragma unroll
    for (int i = 0; i < D / 4; ++i) o4[i] = acc[i];
    float4* op = (float4*)(out_P + (size_t)b * NC);
    op[0] = make_float4(sc[0], sc[1], sc[2], sc[3]);
    op[1] = make_float4(sc[4], sc[5], sc[6], sc[7]);
}

extern "C" void kernel_launch(void* const* d_in, const int* in_sizes, int n_in,
                              void* d_out, int out_size, void* d_ws, size_t ws_size,
                              hipStream_t stream)
{
    const float* emb    = (const float*)d_in[0];
    const float* thetas = (const float*)d_in[1];
    const float* proto  = (const float*)d_in[2];
    const float* a0     = (const float*)d_in[3];
    const float* fa     = (const float*)d_in[4];
    const float* fb     = (const float*)d_in[5];

    const int B = in_sizes[0] / D;           // 131072
    float* out_emb = (float*)d_out;
    float* out_P   = (float*)d_out + (size_t)B * D;

    const size_t table_bytes = TSZ * sizeof(__half);   // ~1.5 MB

    if (ws_size >= table_bytes) {
        __half* T = (__half*)d_ws;
        build_table_kernel<<<NMIN, 256, 0, stream>>>(a0, fa, fb, T);
        // 16 lanes per item: B*16 threads total
        const long long total_threads = (long long)B * 16;
        const int blocks = (int)((total_threads + 255) / 256);
        mix_kernel16<<<blocks, 256, 0, stream>>>(emb, thetas, proto, T, out_emb, out_P, B);
    } else {
        const int blocks = (B + 255) / 256;
        fused_fallback<<<blocks, 256, 0, stream>>>(emb, thetas, proto, a0, fa, fb,
                                                   out_emb, out_P, B);
    }
}